// Round 1
// baseline (590.621 us; speedup 1.0000x reference)
//
#include <hip/hip_runtime.h>
#include <cfloat>

#define NTOK (256 * 2048)   // 524288 tokens
#define D 64
#define K 512
#define CHUNK 128           // embeddings staged per LDS pass (32 KB)
#define TPB 256

// ---------- kernel 1: per-embedding squared norms (balanced tree, f32) ----------
__global__ void vq_senorm_kernel(const float* __restrict__ emb,
                                 float* __restrict__ se) {
    int k = threadIdx.x;            // launched with K threads
    const float4* e4 = (const float4*)(emb + (size_t)k * D);
    float t[D];
#pragma unroll
    for (int q = 0; q < D / 4; ++q) {
        float4 v = e4[q];
        t[4 * q + 0] = __fmul_rn(v.x, v.x);
        t[4 * q + 1] = __fmul_rn(v.y, v.y);
        t[4 * q + 2] = __fmul_rn(v.z, v.z);
        t[4 * q + 3] = __fmul_rn(v.w, v.w);
    }
#pragma unroll
    for (int s = 1; s < D; s <<= 1)
#pragma unroll
        for (int j = 0; j < D; j += 2 * s) t[j] = __fadd_rn(t[j], t[j + s]);
    se[k] = t[0];
}

// ---------- kernel 2: argmin + quantized write + per-block loss partial ----------
__global__ __launch_bounds__(TPB) void vq_main_kernel(
        const float* __restrict__ xg, const float* __restrict__ emb,
        const float* __restrict__ se, float* __restrict__ out,
        float* __restrict__ bsum) {
    __shared__ float lds_e[CHUNK * D];     // 32 KB
    __shared__ float lds_se[CHUNK];
    __shared__ int   lds_kmin[TPB];
    __shared__ float lds_red[TPB / 64];

    const int tid = threadIdx.x;
    const size_t tok = (size_t)blockIdx.x * TPB + tid;

    // ---- load this thread's token into registers ----
    float x[D];
    {
        const float4* xg4 = (const float4*)(xg + tok * D);
#pragma unroll
        for (int q = 0; q < D / 4; ++q) {
            float4 v = xg4[q];
            x[4 * q + 0] = v.x; x[4 * q + 1] = v.y;
            x[4 * q + 2] = v.z; x[4 * q + 3] = v.w;
        }
    }
    // ---- sx = sum(x*x), balanced tree (mimic pairwise reduction) ----
    float sx;
    {
        float t[D];
#pragma unroll
        for (int j = 0; j < D; ++j) t[j] = __fmul_rn(x[j], x[j]);
#pragma unroll
        for (int s = 1; s < D; s <<= 1)
#pragma unroll
            for (int j = 0; j < D; j += 2 * s) t[j] = __fadd_rn(t[j], t[j + s]);
        sx = t[0];
    }

    // ---- argmin over K in LDS chunks ----
    float dmin = FLT_MAX;
    int kmin = 0;

    for (int c = 0; c < K; c += CHUNK) {
        __syncthreads();   // protect lds_e from previous iteration's readers
        {
            const float4* src = (const float4*)(emb + (size_t)c * D);
            float4* dst = (float4*)lds_e;
#pragma unroll
            for (int i = 0; i < (CHUNK * D / 4) / TPB; ++i)
                dst[i * TPB + tid] = src[i * TPB + tid];
            if (tid < CHUNK) lds_se[tid] = se[c + tid];
        }
        __syncthreads();

        for (int kk = 0; kk < CHUNK; ++kk) {
            const float* e = lds_e + kk * D;   // wave-uniform address -> broadcast
            float a0 = 0.f, a1 = 0.f, a2 = 0.f, a3 = 0.f;
#pragma unroll
            for (int j = 0; j < D; j += 4) {
                a0 = __fmaf_rn(x[j + 0], e[j + 0], a0);
                a1 = __fmaf_rn(x[j + 1], e[j + 1], a1);
                a2 = __fmaf_rn(x[j + 2], e[j + 2], a2);
                a3 = __fmaf_rn(x[j + 3], e[j + 3], a3);
            }
            float dot = __fadd_rn(__fadd_rn(a0, a1), __fadd_rn(a2, a3));
            // reference form: (sx + se_k) - 2*dot, exact rounding order
            float d = __fsub_rn(__fadd_rn(sx, lds_se[kk]), __fmul_rn(2.0f, dot));
            if (d < dmin) { dmin = d; kmin = c + kk; }  // strict < keeps lowest index
        }
    }

    // ---- per-token loss partial: sum((q - x)^2) ----
    float lp = 0.f;
    {
        const float4* e4 = (const float4*)(emb + (size_t)kmin * D);
#pragma unroll
        for (int q = 0; q < D / 4; ++q) {
            float4 v = e4[q];
            float d0 = __fsub_rn(v.x, x[4 * q + 0]); lp = __fmaf_rn(d0, d0, lp);
            float d1 = __fsub_rn(v.y, x[4 * q + 1]); lp = __fmaf_rn(d1, d1, lp);
            float d2 = __fsub_rn(v.z, x[4 * q + 2]); lp = __fmaf_rn(d2, d2, lp);
            float d3 = __fsub_rn(v.w, x[4 * q + 3]); lp = __fmaf_rn(d3, d3, lp);
        }
    }

    lds_kmin[tid] = kmin;

    // wave reduce lp (width 64), then cross-wave via LDS — fixed order, deterministic
#pragma unroll
    for (int off = 32; off >= 1; off >>= 1) lp += __shfl_down(lp, off, 64);
    if ((tid & 63) == 0) lds_red[tid >> 6] = lp;
    __syncthreads();
    if (tid == 0) {
        float s = lds_red[0];
#pragma unroll
        for (int w = 1; w < TPB / 64; ++w) s = __fadd_rn(s, lds_red[w]);
        bsum[blockIdx.x] = s;
    }

    // ---- coalesced quantized write: 256 tokens * 16 float4 per block ----
    {
        const float4* emb4 = (const float4*)emb;
        float4* out4 = (float4*)out + (size_t)blockIdx.x * (TPB * D / 4);
#pragma unroll
        for (int it = 0; it < (TPB * D / 4) / TPB; ++it) {
            int m = it * TPB + tid;
            int t = m >> 4;          // token within block
            int q = m & 15;          // float4 within token row
            out4[m] = emb4[(size_t)lds_kmin[t] * 16 + q];
        }
    }
}

// ---------- kernel 3: final deterministic loss reduction ----------
__global__ void vq_loss_kernel(const float* __restrict__ bsum, int nb,
                               float* __restrict__ out_losses) {
    __shared__ float red[256];
    int tid = threadIdx.x;
    float s = 0.f;
    for (int i = tid; i < nb; i += 256) s = __fadd_rn(s, bsum[i]);
    red[tid] = s;
    __syncthreads();
    for (int off = 128; off >= 1; off >>= 1) {
        if (tid < off) red[tid] = __fadd_rn(red[tid], red[tid + off]);
        __syncthreads();
    }
    if (tid == 0) {
        float mean = red[0] / (float)((long long)NTOK * D);
        out_losses[0] = 0.25f * mean;  // commitment_loss
        out_losses[1] = mean;          // embedding_loss
    }
}

extern "C" void kernel_launch(void* const* d_in, const int* in_sizes, int n_in,
                              void* d_out, int out_size, void* d_ws, size_t ws_size,
                              hipStream_t stream) {
    const float* xg  = (const float*)d_in[0];   // inputs  [256,2048,64]
    const float* emb = (const float*)d_in[1];   // embeddings [512,64]
    float* out = (float*)d_out;

    float* se   = (float*)d_ws;   // [K]
    float* bsum = se + K;         // [NTOK/TPB]

    vq_senorm_kernel<<<1, K, 0, stream>>>(emb, se);

    int nb = NTOK / TPB;          // 2048 blocks
    vq_main_kernel<<<nb, TPB, 0, stream>>>(xg, emb, se, out, bsum);

    vq_loss_kernel<<<1, 256, 0, stream>>>(bsum, nb, out + (size_t)NTOK * D);
}

// Round 2
// 424.948 us; speedup vs baseline: 1.3899x; 1.3899x over previous
//
#include <hip/hip_runtime.h>
#include <cfloat>

#define NTOK (256 * 2048)   // 524288 tokens
#define D 64
#define K 512
#define TPB 256

// ---------- kernel 1: per-embedding squared norms (balanced tree, f32) ----------
__global__ void vq_senorm_kernel(const float* __restrict__ emb,
                                 float* __restrict__ se) {
    int k = threadIdx.x;            // launched with K threads
    const float4* e4 = (const float4*)(emb + (size_t)k * D);
    float t[D];
#pragma unroll
    for (int q = 0; q < D / 4; ++q) {
        float4 v = e4[q];
        t[4 * q + 0] = __fmul_rn(v.x, v.x);
        t[4 * q + 1] = __fmul_rn(v.y, v.y);
        t[4 * q + 2] = __fmul_rn(v.z, v.z);
        t[4 * q + 3] = __fmul_rn(v.w, v.w);
    }
#pragma unroll
    for (int s = 1; s < D; s <<= 1)
#pragma unroll
        for (int j = 0; j < D; j += 2 * s) t[j] = __fadd_rn(t[j], t[j + s]);
    se[k] = t[0];
}

// ---------- kernel 2: argmin + quantized write + per-block loss partial ----------
// Embeddings are read via wave-uniform addresses -> compiler promotes to
// s_load (SMEM/scalar cache); FMAs take the e-operand from SGPRs. No LDS
// staging, no per-kk LDS traffic. Arithmetic order identical to round 1.
__global__ __launch_bounds__(TPB) void vq_main_kernel(
        const float* __restrict__ xg, const float* __restrict__ emb,
        const float* __restrict__ se, float* __restrict__ out,
        float* __restrict__ bsum) {
    __shared__ int   lds_kmin[TPB];
    __shared__ float lds_red[TPB / 64];

    const int tid = threadIdx.x;
    const size_t tok = (size_t)blockIdx.x * TPB + tid;

    // ---- load this thread's token into registers ----
    float x[D];
    {
        const float4* xg4 = (const float4*)(xg + tok * D);
#pragma unroll
        for (int q = 0; q < D / 4; ++q) {
            float4 v = xg4[q];
            x[4 * q + 0] = v.x; x[4 * q + 1] = v.y;
            x[4 * q + 2] = v.z; x[4 * q + 3] = v.w;
        }
    }
    // ---- sx = sum(x*x), balanced tree ----
    float sx;
    {
        float t[D];
#pragma unroll
        for (int j = 0; j < D; ++j) t[j] = __fmul_rn(x[j], x[j]);
#pragma unroll
        for (int s = 1; s < D; s <<= 1)
#pragma unroll
            for (int j = 0; j < D; j += 2 * s) t[j] = __fadd_rn(t[j], t[j + s]);
        sx = t[0];
    }

    // ---- argmin over all K codes; e streamed through the scalar pipe ----
    float dmin = FLT_MAX;
    int kmin = 0;

    for (int k = 0; k < K; ++k) {
        const float* ek = emb + (size_t)k * D;   // uniform address -> s_load
        const float sek = se[k];                 // uniform -> s_load
        float a0 = 0.f, a1 = 0.f, a2 = 0.f, a3 = 0.f;
#pragma unroll
        for (int j = 0; j < D; j += 4) {
            a0 = __fmaf_rn(x[j + 0], ek[j + 0], a0);
            a1 = __fmaf_rn(x[j + 1], ek[j + 1], a1);
            a2 = __fmaf_rn(x[j + 2], ek[j + 2], a2);
            a3 = __fmaf_rn(x[j + 3], ek[j + 3], a3);
        }
        float dot = __fadd_rn(__fadd_rn(a0, a1), __fadd_rn(a2, a3));
        // reference form: (sx + se_k) - 2*dot, exact rounding order (== round 1)
        float d = __fsub_rn(__fadd_rn(sx, sek), __fmul_rn(2.0f, dot));
        if (d < dmin) { dmin = d; kmin = k; }    // strict < keeps lowest index
    }

    // ---- per-token loss partial: sum((q - x)^2) ----
    float lp = 0.f;
    {
        const float4* e4 = (const float4*)(emb + (size_t)kmin * D);
#pragma unroll
        for (int q = 0; q < D / 4; ++q) {
            float4 v = e4[q];
            float d0 = __fsub_rn(v.x, x[4 * q + 0]); lp = __fmaf_rn(d0, d0, lp);
            float d1 = __fsub_rn(v.y, x[4 * q + 1]); lp = __fmaf_rn(d1, d1, lp);
            float d2 = __fsub_rn(v.z, x[4 * q + 2]); lp = __fmaf_rn(d2, d2, lp);
            float d3 = __fsub_rn(v.w, x[4 * q + 3]); lp = __fmaf_rn(d3, d3, lp);
        }
    }

    lds_kmin[tid] = kmin;

    // wave reduce lp (width 64), then cross-wave via LDS — fixed order, deterministic
#pragma unroll
    for (int off = 32; off >= 1; off >>= 1) lp += __shfl_down(lp, off, 64);
    if ((tid & 63) == 0) lds_red[tid >> 6] = lp;
    __syncthreads();
    if (tid == 0) {
        float s = lds_red[0];
#pragma unroll
        for (int w = 1; w < TPB / 64; ++w) s = __fadd_rn(s, lds_red[w]);
        bsum[blockIdx.x] = s;
    }

    // ---- coalesced quantized write: 256 tokens * 16 float4 per block ----
    {
        const float4* emb4 = (const float4*)emb;
        float4* out4 = (float4*)out + (size_t)blockIdx.x * (TPB * D / 4);
#pragma unroll
        for (int it = 0; it < (TPB * D / 4) / TPB; ++it) {
            int m = it * TPB + tid;
            int t = m >> 4;          // token within block
            int q = m & 15;          // float4 within token row
            out4[m] = emb4[(size_t)lds_kmin[t] * 16 + q];
        }
    }
}

// ---------- kernel 3: final deterministic loss reduction ----------
__global__ void vq_loss_kernel(const float* __restrict__ bsum, int nb,
                               float* __restrict__ out_losses) {
    __shared__ float red[256];
    int tid = threadIdx.x;
    float s = 0.f;
    for (int i = tid; i < nb; i += 256) s = __fadd_rn(s, bsum[i]);
    red[tid] = s;
    __syncthreads();
    for (int off = 128; off >= 1; off >>= 1) {
        if (tid < off) red[tid] = __fadd_rn(red[tid], red[tid + off]);
        __syncthreads();
    }
    if (tid == 0) {
        float mean = red[0] / (float)((long long)NTOK * D);
        out_losses[0] = 0.25f * mean;  // commitment_loss
        out_losses[1] = mean;          // embedding_loss
    }
}

extern "C" void kernel_launch(void* const* d_in, const int* in_sizes, int n_in,
                              void* d_out, int out_size, void* d_ws, size_t ws_size,
                              hipStream_t stream) {
    const float* xg  = (const float*)d_in[0];   // inputs  [256,2048,64]
    const float* emb = (const float*)d_in[1];   // embeddings [512,64]
    float* out = (float*)d_out;

    float* se   = (float*)d_ws;   // [K]
    float* bsum = se + K;         // [NTOK/TPB]

    vq_senorm_kernel<<<1, K, 0, stream>>>(emb, se);

    int nb = NTOK / TPB;          // 2048 blocks
    vq_main_kernel<<<nb, TPB, 0, stream>>>(xg, emb, se, out, bsum);

    vq_loss_kernel<<<1, 256, 0, stream>>>(bsum, nb, out + (size_t)NTOK * D);
}